// Round 1
// baseline (2962.109 us; speedup 1.0000x reference)
//
#include <hip/hip_runtime.h>

// GCN: N=100000 nodes, E=800000 edges, D=128, two GraphConv layers.
// Layer1: relu((S @ (x * rsqrt(deg_out)) ) @ W1^T + b1) * rsqrt(deg_in) + x), relu
// Layer2: same, no residual / no relu.

#define NN 100000
#define EE 800000
#define DD 128

__global__ __launch_bounds__(256) void degree_kernel(const int* __restrict__ row,
                                                     const int* __restrict__ col,
                                                     int* __restrict__ cnt_out,
                                                     int* __restrict__ cnt_in) {
    int e = blockIdx.x * 256 + threadIdx.x;
    if (e < EE) {
        atomicAdd(&cnt_out[row[e]], 1);
        atomicAdd(&cnt_in[col[e]], 1);
    }
}

__global__ __launch_bounds__(256) void dinv_kernel(const int* __restrict__ cnt_out,
                                                   const int* __restrict__ cnt_in,
                                                   float* __restrict__ dinv_out,
                                                   float* __restrict__ dinv_in) {
    int n = blockIdx.x * 256 + threadIdx.x;
    if (n < NN) {
        dinv_out[n] = rsqrtf((float)max(cnt_out[n], 1));
        dinv_in[n]  = rsqrtf((float)max(cnt_in[n], 1));
    }
}

// 32 threads per edge (32 x float4 = 128 floats). Grid is exactly E*32/256 blocks.
__global__ __launch_bounds__(256) void scatter_kernel(const float* __restrict__ src,
                                                      const int* __restrict__ row,
                                                      const int* __restrict__ col,
                                                      const float* __restrict__ dinv_out,
                                                      float* __restrict__ agg) {
    int t = blockIdx.x * 256 + threadIdx.x;
    int e = t >> 5;
    int c = t & 31;
    int r  = row[e];
    int cl = col[e];
    float s = dinv_out[r];
    float4 v = ((const float4*)(src + (size_t)r * DD))[c];
    float* dst = agg + (size_t)cl * DD + (size_t)c * 4;
    unsafeAtomicAdd(dst + 0, v.x * s);
    unsafeAtomicAdd(dst + 1, v.y * s);
    unsafeAtomicAdd(dst + 2, v.z * s);
    unsafeAtomicAdd(dst + 3, v.w * s);
}

// out[n,j] = epilogue( sum_k A[n,k] * W[j,k] + b[j] )
// Block: 64 rows x 128 cols. 256 threads, each 4 rows x 8 cols.
// LDS: As k-major [32][64] (8KB), Ws k-major [32][128] (16KB).
template <bool RESID, bool RELU>
__global__ __launch_bounds__(256) void gemm_ep(const float* __restrict__ A,
                                               const float* __restrict__ W,
                                               const float* __restrict__ bias,
                                               const float* __restrict__ dinv,
                                               const float* __restrict__ resid,
                                               float* __restrict__ out) {
    __shared__ float As[32 * 64];
    __shared__ float Ws[32 * 128];

    const int tid = threadIdx.x;
    const int jt = tid & 15;   // col group: 8 cols each
    const int it = tid >> 4;   // row group: 4 rows each
    const int row0 = blockIdx.x * 64;

    float acc[4][8];
#pragma unroll
    for (int i = 0; i < 4; ++i)
#pragma unroll
        for (int j = 0; j < 8; ++j) acc[i][j] = 0.f;

    // staging maps
    const int lr = tid >> 2;          // 0..63 row of A tile
    const int lcA = (tid & 3) * 8;    // k chunk of 8
    const int lj = tid >> 1;          // 0..127 row of W
    const int lkW = (tid & 1) * 16;   // k chunk of 16

    for (int kk = 0; kk < DD; kk += 32) {
        // stage A tile (transpose to k-major)
        {
            int gr = row0 + lr;
            int grc = gr < NN ? gr : (NN - 1);
            const float4* src = (const float4*)(A + (size_t)grc * DD + kk + lcA);
            float4 v0 = src[0];
            float4 v1 = src[1];
            if (gr >= NN) { v0 = make_float4(0.f, 0.f, 0.f, 0.f); v1 = v0; }
            As[(lcA + 0) * 64 + lr] = v0.x;
            As[(lcA + 1) * 64 + lr] = v0.y;
            As[(lcA + 2) * 64 + lr] = v0.z;
            As[(lcA + 3) * 64 + lr] = v0.w;
            As[(lcA + 4) * 64 + lr] = v1.x;
            As[(lcA + 5) * 64 + lr] = v1.y;
            As[(lcA + 6) * 64 + lr] = v1.z;
            As[(lcA + 7) * 64 + lr] = v1.w;
        }
        // stage W tile (transpose to k-major)
        {
            const float4* src = (const float4*)(W + (size_t)lj * DD + kk + lkW);
#pragma unroll
            for (int q = 0; q < 4; ++q) {
                float4 v = src[q];
                int k = lkW + q * 4;
                Ws[(k + 0) * 128 + lj] = v.x;
                Ws[(k + 1) * 128 + lj] = v.y;
                Ws[(k + 2) * 128 + lj] = v.z;
                Ws[(k + 3) * 128 + lj] = v.w;
            }
        }
        __syncthreads();

#pragma unroll
        for (int k = 0; k < 32; ++k) {
            float4 a  = *(const float4*)(As + k * 64 + it * 4);
            float4 w0 = *(const float4*)(Ws + k * 128 + jt * 8);
            float4 w1 = *(const float4*)(Ws + k * 128 + jt * 8 + 4);
            float av[4] = {a.x, a.y, a.z, a.w};
            float wv[8] = {w0.x, w0.y, w0.z, w0.w, w1.x, w1.y, w1.z, w1.w};
#pragma unroll
            for (int i = 0; i < 4; ++i)
#pragma unroll
                for (int j = 0; j < 8; ++j) acc[i][j] += av[i] * wv[j];
        }
        __syncthreads();
    }

    // epilogue
    float4 b0 = *(const float4*)(bias + jt * 8);
    float4 b1 = *(const float4*)(bias + jt * 8 + 4);
    float bv[8] = {b0.x, b0.y, b0.z, b0.w, b1.x, b1.y, b1.z, b1.w};

#pragma unroll
    for (int i = 0; i < 4; ++i) {
        int r = row0 + it * 4 + i;
        if (r < NN) {
            float dv = dinv[r];
            float o[8];
#pragma unroll
            for (int j = 0; j < 8; ++j) o[j] = (acc[i][j] + bv[j]) * dv;
            if (RESID) {
                const float4* rp = (const float4*)(resid + (size_t)r * DD + jt * 8);
                float4 r0 = rp[0];
                float4 r1 = rp[1];
                float rv[8] = {r0.x, r0.y, r0.z, r0.w, r1.x, r1.y, r1.z, r1.w};
#pragma unroll
                for (int j = 0; j < 8; ++j) o[j] += rv[j];
            }
            if (RELU) {
#pragma unroll
                for (int j = 0; j < 8; ++j) o[j] = fmaxf(o[j], 0.f);
            }
            float4* op = (float4*)(out + (size_t)r * DD + jt * 8);
            op[0] = make_float4(o[0], o[1], o[2], o[3]);
            op[1] = make_float4(o[4], o[5], o[6], o[7]);
        }
    }
}

extern "C" void kernel_launch(void* const* d_in, const int* in_sizes, int n_in,
                              void* d_out, int out_size, void* d_ws, size_t ws_size,
                              hipStream_t stream) {
    const float* x  = (const float*)d_in[0];
    const int*   ei = (const int*)d_in[1];
    const float* W1 = (const float*)d_in[2];
    const float* b1 = (const float*)d_in[3];
    const float* W2 = (const float*)d_in[4];
    const float* b2 = (const float*)d_in[5];
    float* out = (float*)d_out;

    const int* row = ei;        // edge_index[0]
    const int* col = ei + EE;   // edge_index[1]

    // workspace layout
    float* agg      = (float*)d_ws;                 // N*D floats (51.2 MB)
    float* dinv_out = agg + (size_t)NN * DD;        // N floats
    float* dinv_in  = dinv_out + NN;                // N floats
    int*   cnt      = (int*)(dinv_in + NN);         // 2*N ints

    // degrees (edge-only, computed once per call)
    hipMemsetAsync(cnt, 0, 2 * NN * sizeof(int), stream);
    degree_kernel<<<(EE + 255) / 256, 256, 0, stream>>>(row, col, cnt, cnt + NN);
    dinv_kernel<<<(NN + 255) / 256, 256, 0, stream>>>(cnt, cnt + NN, dinv_out, dinv_in);

    // ---- layer 1 ----
    hipMemsetAsync(agg, 0, (size_t)NN * DD * sizeof(float), stream);
    scatter_kernel<<<(EE * 32) / 256, 256, 0, stream>>>(x, row, col, dinv_out, agg);
    gemm_ep<true, true><<<(NN + 63) / 64, 256, 0, stream>>>(agg, W1, b1, dinv_in, x, out);

    // ---- layer 2 (reads layer-1 output from d_out, overwrites d_out) ----
    hipMemsetAsync(agg, 0, (size_t)NN * DD * sizeof(float), stream);
    scatter_kernel<<<(EE * 32) / 256, 256, 0, stream>>>(out, row, col, dinv_out, agg);
    gemm_ep<false, false><<<(NN + 63) / 64, 256, 0, stream>>>(agg, W2, b2, dinv_in, nullptr, out);
}

// Round 2
// 443.711 us; speedup vs baseline: 6.6758x; 6.6758x over previous
//
#include <hip/hip_runtime.h>

// GCN: N=100000 nodes, E=800000 edges, D=128, two GraphConv layers.
// R2: atomic scatter (1.6 GB HBM write amplification, 1345us/layer) replaced by
// CSR build (histogram + scan + fill) and a deterministic per-node gather.

#define NN 100000
#define EE 800000
#define DD 128
#define NB1 98            // ceil(NN / 1024) blocks for scan level 1

__global__ __launch_bounds__(256) void degree_kernel(const int* __restrict__ row,
                                                     const int* __restrict__ col,
                                                     int* __restrict__ cnt_out,
                                                     int* __restrict__ cnt_in) {
    int e = blockIdx.x * 256 + threadIdx.x;
    if (e < EE) {
        atomicAdd(&cnt_out[row[e]], 1);
        atomicAdd(&cnt_in[col[e]], 1);
    }
}

__global__ __launch_bounds__(256) void dinv_kernel(const int* __restrict__ cnt_out,
                                                   const int* __restrict__ cnt_in,
                                                   float* __restrict__ dinv_out,
                                                   float* __restrict__ dinv_in) {
    int n = blockIdx.x * 256 + threadIdx.x;
    if (n < NN) {
        dinv_out[n] = rsqrtf((float)max(cnt_out[n], 1));
        dinv_in[n]  = rsqrtf((float)max(cnt_in[n], 1));
    }
}

// ---- exclusive scan of cnt_in over NN elements (3-level) ----
__global__ __launch_bounds__(256) void scan1_kernel(const int* __restrict__ cnt,
                                                    int* __restrict__ excl,
                                                    int* __restrict__ bsums) {
    __shared__ int tmp[256];
    const int t = threadIdx.x;
    const int base = blockIdx.x * 1024 + t * 4;
    int a[4];
#pragma unroll
    for (int q = 0; q < 4; ++q) a[q] = (base + q < NN) ? cnt[base + q] : 0;
    int s = a[0] + a[1] + a[2] + a[3];
    tmp[t] = s;
    __syncthreads();
    for (int off = 1; off < 256; off <<= 1) {
        int v = 0;
        if (t >= off) v = tmp[t - off];
        __syncthreads();
        tmp[t] += v;
        __syncthreads();
    }
    int excl_s = tmp[t] - s;
    if (t == 255) bsums[blockIdx.x] = tmp[t];
    int run = excl_s;
#pragma unroll
    for (int q = 0; q < 4; ++q) {
        if (base + q < NN) excl[base + q] = run;
        run += a[q];
    }
}

__global__ __launch_bounds__(256) void scan2_kernel(int* __restrict__ bsums,
                                                    int nb) {
    __shared__ int tmp[256];
    const int t = threadIdx.x;
    int s = (t < nb) ? bsums[t] : 0;
    tmp[t] = s;
    __syncthreads();
    for (int off = 1; off < 256; off <<= 1) {
        int v = 0;
        if (t >= off) v = tmp[t - off];
        __syncthreads();
        tmp[t] += v;
        __syncthreads();
    }
    if (t < nb) bsums[t] = tmp[t] - s;   // exclusive
}

__global__ __launch_bounds__(256) void scan3_kernel(int* __restrict__ excl,
                                                    const int* __restrict__ bsums,
                                                    int* __restrict__ row_start,
                                                    int* __restrict__ cursor) {
    int i = blockIdx.x * 256 + threadIdx.x;
    if (i < NN) {
        int v = excl[i] + bsums[i >> 10];
        row_start[i] = v;
        cursor[i] = v;
    }
}

__global__ __launch_bounds__(256) void fill_kernel(const int* __restrict__ row,
                                                   const int* __restrict__ col,
                                                   int* __restrict__ cursor,
                                                   int* __restrict__ srcs) {
    int e = blockIdx.x * 256 + threadIdx.x;
    if (e < EE) {
        int p = atomicAdd(&cursor[col[e]], 1);
        srcs[p] = row[e];
    }
}

// ---- gather: one 32-lane half-wave per node, float4 per lane ----
__global__ __launch_bounds__(256) void gather_kernel(const float* __restrict__ src,
                                                     const int* __restrict__ row_start,
                                                     const int* __restrict__ srcs,
                                                     const float* __restrict__ dinv_out,
                                                     float* __restrict__ agg) {
    const int node = blockIdx.x * 8 + (threadIdx.x >> 5);
    const int lane = threadIdx.x & 31;
    if (node >= NN) return;
    int p = row_start[node];
    const int end = (node + 1 < NN) ? row_start[node + 1] : EE;
    float4 acc = make_float4(0.f, 0.f, 0.f, 0.f);
    for (; p + 1 < end; p += 2) {
        int s0 = srcs[p];
        int s1 = srcs[p + 1];
        float c0 = dinv_out[s0];
        float c1 = dinv_out[s1];
        float4 v0 = ((const float4*)(src + (size_t)s0 * DD))[lane];
        float4 v1 = ((const float4*)(src + (size_t)s1 * DD))[lane];
        acc.x += v0.x * c0 + v1.x * c1;
        acc.y += v0.y * c0 + v1.y * c1;
        acc.z += v0.z * c0 + v1.z * c1;
        acc.w += v0.w * c0 + v1.w * c1;
    }
    if (p < end) {
        int s0 = srcs[p];
        float c0 = dinv_out[s0];
        float4 v0 = ((const float4*)(src + (size_t)s0 * DD))[lane];
        acc.x += v0.x * c0;
        acc.y += v0.y * c0;
        acc.z += v0.z * c0;
        acc.w += v0.w * c0;
    }
    ((float4*)(agg + (size_t)node * DD))[lane] = acc;
}

// out[n,j] = epilogue( sum_k A[n,k] * W[j,k] + b[j] )
// Block: 64 rows x 128 cols. 256 threads, each 4 rows x 8 cols.
template <bool RESID, bool RELU>
__global__ __launch_bounds__(256) void gemm_ep(const float* __restrict__ A,
                                               const float* __restrict__ W,
                                               const float* __restrict__ bias,
                                               const float* __restrict__ dinv,
                                               const float* __restrict__ resid,
                                               float* __restrict__ out) {
    __shared__ float As[32 * 64];
    __shared__ float Ws[32 * 128];

    const int tid = threadIdx.x;
    const int jt = tid & 15;   // col group: 8 cols each
    const int it = tid >> 4;   // row group: 4 rows each
    const int row0 = blockIdx.x * 64;

    float acc[4][8];
#pragma unroll
    for (int i = 0; i < 4; ++i)
#pragma unroll
        for (int j = 0; j < 8; ++j) acc[i][j] = 0.f;

    const int lr = tid >> 2;          // 0..63 row of A tile
    const int lcA = (tid & 3) * 8;    // k chunk of 8
    const int lj = tid >> 1;          // 0..127 row of W
    const int lkW = (tid & 1) * 16;   // k chunk of 16

    for (int kk = 0; kk < DD; kk += 32) {
        {
            int gr = row0 + lr;
            int grc = gr < NN ? gr : (NN - 1);
            const float4* src = (const float4*)(A + (size_t)grc * DD + kk + lcA);
            float4 v0 = src[0];
            float4 v1 = src[1];
            if (gr >= NN) { v0 = make_float4(0.f, 0.f, 0.f, 0.f); v1 = v0; }
            As[(lcA + 0) * 64 + lr] = v0.x;
            As[(lcA + 1) * 64 + lr] = v0.y;
            As[(lcA + 2) * 64 + lr] = v0.z;
            As[(lcA + 3) * 64 + lr] = v0.w;
            As[(lcA + 4) * 64 + lr] = v1.x;
            As[(lcA + 5) * 64 + lr] = v1.y;
            As[(lcA + 6) * 64 + lr] = v1.z;
            As[(lcA + 7) * 64 + lr] = v1.w;
        }
        {
            const float4* src = (const float4*)(W + (size_t)lj * DD + kk + lkW);
#pragma unroll
            for (int q = 0; q < 4; ++q) {
                float4 v = src[q];
                int k = lkW + q * 4;
                Ws[(k + 0) * 128 + lj] = v.x;
                Ws[(k + 1) * 128 + lj] = v.y;
                Ws[(k + 2) * 128 + lj] = v.z;
                Ws[(k + 3) * 128 + lj] = v.w;
            }
        }
        __syncthreads();

#pragma unroll
        for (int k = 0; k < 32; ++k) {
            float4 a  = *(const float4*)(As + k * 64 + it * 4);
            float4 w0 = *(const float4*)(Ws + k * 128 + jt * 8);
            float4 w1 = *(const float4*)(Ws + k * 128 + jt * 8 + 4);
            float av[4] = {a.x, a.y, a.z, a.w};
            float wv[8] = {w0.x, w0.y, w0.z, w0.w, w1.x, w1.y, w1.z, w1.w};
#pragma unroll
            for (int i = 0; i < 4; ++i)
#pragma unroll
                for (int j = 0; j < 8; ++j) acc[i][j] += av[i] * wv[j];
        }
        __syncthreads();
    }

    float4 b0 = *(const float4*)(bias + jt * 8);
    float4 b1 = *(const float4*)(bias + jt * 8 + 4);
    float bv[8] = {b0.x, b0.y, b0.z, b0.w, b1.x, b1.y, b1.z, b1.w};

#pragma unroll
    for (int i = 0; i < 4; ++i) {
        int r = row0 + it * 4 + i;
        if (r < NN) {
            float dv = dinv[r];
            float o[8];
#pragma unroll
            for (int j = 0; j < 8; ++j) o[j] = (acc[i][j] + bv[j]) * dv;
            if (RESID) {
                const float4* rp = (const float4*)(resid + (size_t)r * DD + jt * 8);
                float4 r0 = rp[0];
                float4 r1 = rp[1];
                float rv[8] = {r0.x, r0.y, r0.z, r0.w, r1.x, r1.y, r1.z, r1.w};
#pragma unroll
                for (int j = 0; j < 8; ++j) o[j] += rv[j];
            }
            if (RELU) {
#pragma unroll
                for (int j = 0; j < 8; ++j) o[j] = fmaxf(o[j], 0.f);
            }
            float4* op = (float4*)(out + (size_t)r * DD + jt * 8);
            op[0] = make_float4(o[0], o[1], o[2], o[3]);
            op[1] = make_float4(o[4], o[5], o[6], o[7]);
        }
    }
}

extern "C" void kernel_launch(void* const* d_in, const int* in_sizes, int n_in,
                              void* d_out, int out_size, void* d_ws, size_t ws_size,
                              hipStream_t stream) {
    const float* x  = (const float*)d_in[0];
    const int*   ei = (const int*)d_in[1];
    const float* W1 = (const float*)d_in[2];
    const float* b1 = (const float*)d_in[3];
    const float* W2 = (const float*)d_in[4];
    const float* b2 = (const float*)d_in[5];
    float* out = (float*)d_out;

    const int* row = ei;        // edge_index[0] (source)
    const int* col = ei + EE;   // edge_index[1] (target)

    // workspace layout
    float* agg      = (float*)d_ws;                 // N*D floats (51.2 MB)
    float* dinv_out = agg + (size_t)NN * DD;        // N
    float* dinv_in  = dinv_out + NN;                // N
    int*   cnt      = (int*)(dinv_in + NN);         // 2*N (cnt_out, cnt_in)
    int*   excl     = cnt + 2 * NN;                 // N
    int*   row_st   = excl + NN;                    // N
    int*   cursor   = row_st + NN;                  // N
    int*   srcs     = cursor + NN;                  // E
    int*   bsums    = srcs + EE;                    // 256

    // ---- degrees + CSR build (once, reused by both layers) ----
    hipMemsetAsync(cnt, 0, 2 * NN * sizeof(int), stream);
    degree_kernel<<<(EE + 255) / 256, 256, 0, stream>>>(row, col, cnt, cnt + NN);
    dinv_kernel<<<(NN + 255) / 256, 256, 0, stream>>>(cnt, cnt + NN, dinv_out, dinv_in);
    scan1_kernel<<<NB1, 256, 0, stream>>>(cnt + NN, excl, bsums);
    scan2_kernel<<<1, 256, 0, stream>>>(bsums, NB1);
    scan3_kernel<<<(NN + 255) / 256, 256, 0, stream>>>(excl, bsums, row_st, cursor);
    fill_kernel<<<(EE + 255) / 256, 256, 0, stream>>>(row, col, cursor, srcs);

    // ---- layer 1 ----
    gather_kernel<<<(NN + 7) / 8, 256, 0, stream>>>(x, row_st, srcs, dinv_out, agg);
    gemm_ep<true, true><<<(NN + 63) / 64, 256, 0, stream>>>(agg, W1, b1, dinv_in, x, out);

    // ---- layer 2 ----
    gather_kernel<<<(NN + 7) / 8, 256, 0, stream>>>(out, row_st, srcs, dinv_out, agg);
    gemm_ep<false, false><<<(NN + 63) / 64, 256, 0, stream>>>(agg, W2, b2, dinv_in, nullptr, out);
}

// Round 3
// 357.374 us; speedup vs baseline: 8.2885x; 1.2416x over previous
//
#include <hip/hip_runtime.h>

// GCN: N=100000, E=800000, D=128, two GraphConv layers.
// R3: bf16 gather path (halves random-row fetch traffic) + MFMA bf16 GEMM.
// Layer-1 output stored only as prescaled bf16 (hs = h * rsqrt(deg_out)),
// aliased over the dead xb buffer.

#define NN 100000
#define EE 800000
#define DD 128
#define NB1 98            // ceil(NN / 1024) blocks for scan level 1
#define NTILE (NN / 16)   // 6250 MFMA row-tiles (NN % 16 == 0)

typedef __attribute__((ext_vector_type(8))) short short8;
typedef __attribute__((ext_vector_type(4))) float floatx4;

__device__ inline float bf2f(unsigned int u16) {
    union { unsigned int i; float f; } c;
    c.i = u16 << 16;
    return c.f;
}
__device__ inline ushort f2bf(float f) {
    union { float f; unsigned int i; } c;
    c.f = f;
    unsigned int u = c.i;
    return (ushort)((u + 0x7fffu + ((u >> 16) & 1u)) >> 16);  // RNE
}

// ---------------- degree + dinv ----------------
__global__ __launch_bounds__(256) void degree_kernel(const int* __restrict__ row,
                                                     const int* __restrict__ col,
                                                     int* __restrict__ cnt_out,
                                                     int* __restrict__ cnt_in) {
    int e = blockIdx.x * 256 + threadIdx.x;
    if (e < EE) {
        atomicAdd(&cnt_out[row[e]], 1);
        atomicAdd(&cnt_in[col[e]], 1);
    }
}

__global__ __launch_bounds__(256) void dinv_kernel(const int* __restrict__ cnt_out,
                                                   const int* __restrict__ cnt_in,
                                                   float* __restrict__ dinv_out,
                                                   float* __restrict__ dinv_in) {
    int n = blockIdx.x * 256 + threadIdx.x;
    if (n < NN) {
        dinv_out[n] = rsqrtf((float)max(cnt_out[n], 1));
        dinv_in[n]  = rsqrtf((float)max(cnt_in[n], 1));
    }
}

// ---------------- exclusive scan of cnt_in (3-level) ----------------
__global__ __launch_bounds__(256) void scan1_kernel(const int* __restrict__ cnt,
                                                    int* __restrict__ excl,
                                                    int* __restrict__ bsums) {
    __shared__ int tmp[256];
    const int t = threadIdx.x;
    const int base = blockIdx.x * 1024 + t * 4;
    int a[4];
#pragma unroll
    for (int q = 0; q < 4; ++q) a[q] = (base + q < NN) ? cnt[base + q] : 0;
    int s = a[0] + a[1] + a[2] + a[3];
    tmp[t] = s;
    __syncthreads();
    for (int off = 1; off < 256; off <<= 1) {
        int v = 0;
        if (t >= off) v = tmp[t - off];
        __syncthreads();
        tmp[t] += v;
        __syncthreads();
    }
    int excl_s = tmp[t] - s;
    if (t == 255) bsums[blockIdx.x] = tmp[t];
    int run = excl_s;
#pragma unroll
    for (int q = 0; q < 4; ++q) {
        if (base + q < NN) excl[base + q] = run;
        run += a[q];
    }
}

__global__ __launch_bounds__(256) void scan2_kernel(int* __restrict__ bsums, int nb) {
    __shared__ int tmp[256];
    const int t = threadIdx.x;
    int s = (t < nb) ? bsums[t] : 0;
    tmp[t] = s;
    __syncthreads();
    for (int off = 1; off < 256; off <<= 1) {
        int v = 0;
        if (t >= off) v = tmp[t - off];
        __syncthreads();
        tmp[t] += v;
        __syncthreads();
    }
    if (t < nb) bsums[t] = tmp[t] - s;   // exclusive
}

__global__ __launch_bounds__(256) void scan3_kernel(int* __restrict__ excl,
                                                    const int* __restrict__ bsums,
                                                    int* __restrict__ row_start,
                                                    int* __restrict__ cursor) {
    int i = blockIdx.x * 256 + threadIdx.x;
    if (i < NN) {
        int v = excl[i] + bsums[i >> 10];
        row_start[i] = v;
        cursor[i] = v;
    }
}

__global__ __launch_bounds__(256) void fill_kernel(const int* __restrict__ row,
                                                   const int* __restrict__ col,
                                                   int* __restrict__ cursor,
                                                   int* __restrict__ srcs) {
    int e = blockIdx.x * 256 + threadIdx.x;
    if (e < EE) {
        int p = atomicAdd(&cursor[col[e]], 1);
        srcs[p] = row[e];
    }
}

// ---------------- xb = bf16(x * dinv_out) ----------------
__global__ __launch_bounds__(256) void prescale_kernel(const float* __restrict__ x,
                                                       const float* __restrict__ dinv_out,
                                                       ushort* __restrict__ xb) {
    int idx = blockIdx.x * 256 + threadIdx.x;   // one float4 per thread
    if (idx >= NN * 32) return;
    int n = idx >> 5;
    float s = dinv_out[n];
    float4 v = ((const float4*)x)[idx];
    ushort4 o;
    o.x = f2bf(v.x * s);
    o.y = f2bf(v.y * s);
    o.z = f2bf(v.z * s);
    o.w = f2bf(v.w * s);
    ((ushort4*)xb)[idx] = o;
}

// ---------------- gather: 32 lanes/node, bf16 rows, fp32 accumulate ----------------
__global__ __launch_bounds__(256) void gather_kernel(const ushort* __restrict__ src,
                                                     const int* __restrict__ row_start,
                                                     const int* __restrict__ srcs,
                                                     ushort* __restrict__ agg) {
    const int node = blockIdx.x * 8 + (threadIdx.x >> 5);
    const int lane = threadIdx.x & 31;
    if (node >= NN) return;
    int p = row_start[node];
    const int end = (node + 1 < NN) ? row_start[node + 1] : EE;
    float a0 = 0.f, a1 = 0.f, a2 = 0.f, a3 = 0.f;
    for (; p + 1 < end; p += 2) {
        int s0 = srcs[p];
        int s1 = srcs[p + 1];
        uint2 v0 = ((const uint2*)(src + (size_t)s0 * DD))[lane];
        uint2 v1 = ((const uint2*)(src + (size_t)s1 * DD))[lane];
        a0 += bf2f(v0.x & 0xffffu) + bf2f(v1.x & 0xffffu);
        a1 += bf2f(v0.x >> 16)     + bf2f(v1.x >> 16);
        a2 += bf2f(v0.y & 0xffffu) + bf2f(v1.y & 0xffffu);
        a3 += bf2f(v0.y >> 16)     + bf2f(v1.y >> 16);
    }
    if (p < end) {
        int s0 = srcs[p];
        uint2 v0 = ((const uint2*)(src + (size_t)s0 * DD))[lane];
        a0 += bf2f(v0.x & 0xffffu);
        a1 += bf2f(v0.x >> 16);
        a2 += bf2f(v0.y & 0xffffu);
        a3 += bf2f(v0.y >> 16);
    }
    uint2 o;
    o.x = (unsigned int)f2bf(a0) | ((unsigned int)f2bf(a1) << 16);
    o.y = (unsigned int)f2bf(a2) | ((unsigned int)f2bf(a3) << 16);
    ((uint2*)(agg + (size_t)node * DD))[lane] = o;
}

// ---------------- MFMA bf16 GEMM + epilogue ----------------
// C[m, j] = sum_k agg[m,k] * W[j,k]   (W row-major [j][k] == B^T input)
// Block: 256 threads = 4 waves, each wave one 16-row tile x all 128 cols.
// W staged fp32->bf16 into LDS, rows padded to 136 (2-way conflict only).
// A-frags loaded directly from global (each agg row touched by exactly one wave).
template <bool L1>
__global__ __launch_bounds__(256) void gemm_ep(const ushort* __restrict__ agg,
                                               const float* __restrict__ W,
                                               const float* __restrict__ bias,
                                               const float* __restrict__ dinv_in,
                                               const float* __restrict__ dinv_out,
                                               const float* __restrict__ x,
                                               ushort* __restrict__ hs,
                                               float* __restrict__ out) {
    __shared__ ushort Ws[128 * 136];
    {   // stage W (fp32 -> bf16) into LDS
        int j = threadIdx.x >> 1;
        int k0 = (threadIdx.x & 1) * 64;
        const float4* wp = (const float4*)(W + (size_t)j * DD + k0);
        ushort* dst = Ws + j * 136 + k0;
#pragma unroll
        for (int q = 0; q < 16; ++q) {
            float4 v = wp[q];
            ushort4 o;
            o.x = f2bf(v.x); o.y = f2bf(v.y); o.z = f2bf(v.z); o.w = f2bf(v.w);
            *(ushort4*)(dst + q * 4) = o;
        }
    }
    __syncthreads();

    const int wave = threadIdx.x >> 6;
    const int lane = threadIdx.x & 63;
    const int tile = blockIdx.x * 4 + wave;
    if (tile >= NTILE) return;
    const int mi = lane & 15;
    const int quad = lane >> 4;
    const int m0 = tile * 16;

    floatx4 acc[8];
#pragma unroll
    for (int t = 0; t < 8; ++t) acc[t] = (floatx4){0.f, 0.f, 0.f, 0.f};

    const ushort* ap = agg + (size_t)(m0 + mi) * DD + quad * 8;
#pragma unroll
    for (int s = 0; s < 4; ++s) {
        short8 a = *(const short8*)(ap + s * 32);
#pragma unroll
        for (int t = 0; t < 8; ++t) {
            short8 b = *(const short8*)(Ws + (t * 16 + mi) * 136 + s * 32 + quad * 8);
            acc[t] = __builtin_amdgcn_mfma_f32_16x16x32_bf16(a, b, acc[t], 0, 0, 0);
        }
    }

    // C/D layout: col = lane&15, row = quad*4 + reg
    float dv[4], dov[4];
#pragma unroll
    for (int i = 0; i < 4; ++i) {
        int r = m0 + quad * 4 + i;
        dv[i] = dinv_in[r];
        if (L1) dov[i] = dinv_out[r];
    }
#pragma unroll
    for (int t = 0; t < 8; ++t) {
        int c = t * 16 + mi;
        float bv = bias[c];
#pragma unroll
        for (int i = 0; i < 4; ++i) {
            int r = m0 + quad * 4 + i;
            float o = (acc[t][i] + bv) * dv[i];
            if (L1) {
                o += x[(size_t)r * DD + c];
                o = fmaxf(o, 0.f);
                hs[(size_t)r * DD + c] = f2bf(o * dov[i]);
            } else {
                out[(size_t)r * DD + c] = o;
            }
        }
    }
}

extern "C" void kernel_launch(void* const* d_in, const int* in_sizes, int n_in,
                              void* d_out, int out_size, void* d_ws, size_t ws_size,
                              hipStream_t stream) {
    const float* x  = (const float*)d_in[0];
    const int*   ei = (const int*)d_in[1];
    const float* W1 = (const float*)d_in[2];
    const float* b1 = (const float*)d_in[3];
    const float* W2 = (const float*)d_in[4];
    const float* b2 = (const float*)d_in[5];
    float* out = (float*)d_out;

    const int* row = ei;        // edge_index[0] (source)
    const int* col = ei + EE;   // edge_index[1] (target)

    // workspace layout (bf16 buffers first; xb aliased as hs after gather1)
    ushort* agg     = (ushort*)d_ws;                 // N*DD bf16 (25.6 MB)
    ushort* xb      = agg + (size_t)NN * DD;         // N*DD bf16 (25.6 MB) -> becomes hs
    float* dinv_out = (float*)(xb + (size_t)NN * DD);
    float* dinv_in  = dinv_out + NN;
    int*   cnt      = (int*)(dinv_in + NN);          // 2*N
    int*   excl     = cnt + 2 * NN;                  // N
    int*   row_st   = excl + NN;                     // N
    int*   cursor   = row_st + NN;                   // N
    int*   srcs     = cursor + NN;                   // E
    int*   bsums    = srcs + EE;                     // 256

    // ---- degrees + CSR build (reused by both layers) ----
    hipMemsetAsync(cnt, 0, 2 * NN * sizeof(int), stream);
    degree_kernel<<<(EE + 255) / 256, 256, 0, stream>>>(row, col, cnt, cnt + NN);
    dinv_kernel<<<(NN + 255) / 256, 256, 0, stream>>>(cnt, cnt + NN, dinv_out, dinv_in);
    scan1_kernel<<<NB1, 256, 0, stream>>>(cnt + NN, excl, bsums);
    scan2_kernel<<<1, 256, 0, stream>>>(bsums, NB1);
    scan3_kernel<<<(NN + 255) / 256, 256, 0, stream>>>(excl, bsums, row_st, cursor);
    fill_kernel<<<(EE + 255) / 256, 256, 0, stream>>>(row, col, cursor, srcs);

    // ---- layer 1 ----
    prescale_kernel<<<(NN * 32 + 255) / 256, 256, 0, stream>>>(x, dinv_out, xb);
    gather_kernel<<<(NN + 7) / 8, 256, 0, stream>>>(xb, row_st, srcs, agg);
    gemm_ep<true><<<(NTILE + 3) / 4, 256, 0, stream>>>(agg, W1, b1, dinv_in, dinv_out, x,
                                                       /*hs=*/xb, /*out=*/nullptr);

    // ---- layer 2 ----
    gather_kernel<<<(NN + 7) / 8, 256, 0, stream>>>(xb, row_st, srcs, agg);
    gemm_ep<false><<<(NTILE + 3) / 4, 256, 0, stream>>>(agg, W2, b2, dinv_in, nullptr, nullptr,
                                                        nullptr, out);
}

// Round 4
// 315.056 us; speedup vs baseline: 9.4018x; 1.1343x over previous
//
#include <hip/hip_runtime.h>

// GCN: N=100000, E=800000, D=128, two GraphConv layers.
// R4: fused count kernel (atomic return value = CSR slot offset) makes the
// fill pass atomic-free (3 -> 2 atomic passes over edges). Gather uses
// 16 lanes x uint4 with 4-edge unroll for more memory-level parallelism.

#define NN 100000
#define EE 800000
#define DD 128
#define NB1 98            // ceil(NN / 1024) blocks for scan level 1
#define NTILE (NN / 16)   // 6250 MFMA row-tiles (NN % 16 == 0)

typedef __attribute__((ext_vector_type(8))) short short8;
typedef __attribute__((ext_vector_type(4))) float floatx4;

__device__ inline float bf2f(unsigned int u16) {
    union { unsigned int i; float f; } c;
    c.i = u16 << 16;
    return c.f;
}
__device__ inline ushort f2bf(float f) {
    union { float f; unsigned int i; } c;
    c.f = f;
    unsigned int u = c.i;
    return (ushort)((u + 0x7fffu + ((u >> 16) & 1u)) >> 16);  // RNE
}

// ---------------- fused degree count + CSR slot offsets ----------------
__global__ __launch_bounds__(256) void count_kernel(const int* __restrict__ row,
                                                    const int* __restrict__ col,
                                                    int* __restrict__ cnt_out,
                                                    int* __restrict__ cnt_in,
                                                    int* __restrict__ off) {
    int e = blockIdx.x * 256 + threadIdx.x;
    if (e < EE) {
        off[e] = atomicAdd(&cnt_in[col[e]], 1);   // slot within target node
        atomicAdd(&cnt_out[row[e]], 1);
    }
}

__global__ __launch_bounds__(256) void dinv_kernel(const int* __restrict__ cnt_out,
                                                   const int* __restrict__ cnt_in,
                                                   float* __restrict__ dinv_out,
                                                   float* __restrict__ dinv_in) {
    int n = blockIdx.x * 256 + threadIdx.x;
    if (n < NN) {
        dinv_out[n] = rsqrtf((float)max(cnt_out[n], 1));
        dinv_in[n]  = rsqrtf((float)max(cnt_in[n], 1));
    }
}

// ---------------- exclusive scan of cnt_in (3-level) ----------------
__global__ __launch_bounds__(256) void scan1_kernel(const int* __restrict__ cnt,
                                                    int* __restrict__ excl,
                                                    int* __restrict__ bsums) {
    __shared__ int tmp[256];
    const int t = threadIdx.x;
    const int base = blockIdx.x * 1024 + t * 4;
    int a[4];
#pragma unroll
    for (int q = 0; q < 4; ++q) a[q] = (base + q < NN) ? cnt[base + q] : 0;
    int s = a[0] + a[1] + a[2] + a[3];
    tmp[t] = s;
    __syncthreads();
    for (int off = 1; off < 256; off <<= 1) {
        int v = 0;
        if (t >= off) v = tmp[t - off];
        __syncthreads();
        tmp[t] += v;
        __syncthreads();
    }
    int excl_s = tmp[t] - s;
    if (t == 255) bsums[blockIdx.x] = tmp[t];
    int run = excl_s;
#pragma unroll
    for (int q = 0; q < 4; ++q) {
        if (base + q < NN) excl[base + q] = run;
        run += a[q];
    }
}

__global__ __launch_bounds__(256) void scan2_kernel(int* __restrict__ bsums, int nb) {
    __shared__ int tmp[256];
    const int t = threadIdx.x;
    int s = (t < nb) ? bsums[t] : 0;
    tmp[t] = s;
    __syncthreads();
    for (int off = 1; off < 256; off <<= 1) {
        int v = 0;
        if (t >= off) v = tmp[t - off];
        __syncthreads();
        tmp[t] += v;
        __syncthreads();
    }
    if (t < nb) bsums[t] = tmp[t] - s;   // exclusive
}

__global__ __launch_bounds__(256) void scan3_kernel(const int* __restrict__ excl,
                                                    const int* __restrict__ bsums,
                                                    int* __restrict__ row_start) {
    int i = blockIdx.x * 256 + threadIdx.x;
    if (i < NN) row_start[i] = excl[i] + bsums[i >> 10];
}

// ---------------- atomic-free CSR fill ----------------
__global__ __launch_bounds__(256) void fill_kernel(const int* __restrict__ row,
                                                   const int* __restrict__ col,
                                                   const int* __restrict__ row_start,
                                                   const int* __restrict__ off,
                                                   int* __restrict__ srcs) {
    int e = blockIdx.x * 256 + threadIdx.x;
    if (e < EE) srcs[row_start[col[e]] + off[e]] = row[e];
}

// ---------------- xb = bf16(x * dinv_out) ----------------
__global__ __launch_bounds__(256) void prescale_kernel(const float* __restrict__ x,
                                                       const float* __restrict__ dinv_out,
                                                       ushort* __restrict__ xb) {
    int idx = blockIdx.x * 256 + threadIdx.x;   // one float4 per thread
    if (idx >= NN * 32) return;
    int n = idx >> 5;
    float s = dinv_out[n];
    float4 v = ((const float4*)x)[idx];
    ushort4 o;
    o.x = f2bf(v.x * s);
    o.y = f2bf(v.y * s);
    o.z = f2bf(v.z * s);
    o.w = f2bf(v.w * s);
    ((ushort4*)xb)[idx] = o;
}

// ---------------- gather: 16 lanes/node, uint4 (16B) per lane, 4-edge unroll ----------------
__global__ __launch_bounds__(256) void gather_kernel(const ushort* __restrict__ src,
                                                     const int* __restrict__ row_start,
                                                     const int* __restrict__ srcs,
                                                     ushort* __restrict__ agg) {
    const int node = blockIdx.x * 16 + (threadIdx.x >> 4);
    const int lane = threadIdx.x & 15;
    if (node >= NN) return;
    int p = row_start[node];
    const int end = (node + 1 < NN) ? row_start[node + 1] : EE;
    float a0 = 0.f, a1 = 0.f, a2 = 0.f, a3 = 0.f;
    float a4 = 0.f, a5 = 0.f, a6 = 0.f, a7 = 0.f;

#define ACCUM(V)                                     \
    do {                                             \
        a0 += bf2f((V).x & 0xffffu);                 \
        a1 += bf2f((V).x >> 16);                     \
        a2 += bf2f((V).y & 0xffffu);                 \
        a3 += bf2f((V).y >> 16);                     \
        a4 += bf2f((V).z & 0xffffu);                 \
        a5 += bf2f((V).z >> 16);                     \
        a6 += bf2f((V).w & 0xffffu);                 \
        a7 += bf2f((V).w >> 16);                     \
    } while (0)

    for (; p + 3 < end; p += 4) {
        int s0 = srcs[p];
        int s1 = srcs[p + 1];
        int s2 = srcs[p + 2];
        int s3 = srcs[p + 3];
        uint4 v0 = ((const uint4*)(src + (size_t)s0 * DD))[lane];
        uint4 v1 = ((const uint4*)(src + (size_t)s1 * DD))[lane];
        uint4 v2 = ((const uint4*)(src + (size_t)s2 * DD))[lane];
        uint4 v3 = ((const uint4*)(src + (size_t)s3 * DD))[lane];
        ACCUM(v0); ACCUM(v1); ACCUM(v2); ACCUM(v3);
    }
    for (; p < end; ++p) {
        int s0 = srcs[p];
        uint4 v0 = ((const uint4*)(src + (size_t)s0 * DD))[lane];
        ACCUM(v0);
    }
#undef ACCUM

    uint4 o;
    o.x = (unsigned int)f2bf(a0) | ((unsigned int)f2bf(a1) << 16);
    o.y = (unsigned int)f2bf(a2) | ((unsigned int)f2bf(a3) << 16);
    o.z = (unsigned int)f2bf(a4) | ((unsigned int)f2bf(a5) << 16);
    o.w = (unsigned int)f2bf(a6) | ((unsigned int)f2bf(a7) << 16);
    ((uint4*)(agg + (size_t)node * DD))[lane] = o;
}

// ---------------- MFMA bf16 GEMM + epilogue ----------------
// C[m, j] = sum_k agg[m,k] * W[j,k]   (W row-major [j][k] == B^T input)
// Block: 256 threads = 4 waves, each wave one 16-row tile x all 128 cols.
// W staged fp32->bf16 into LDS, rows padded to 136 (2-way conflict only).
template <bool L1>
__global__ __launch_bounds__(256) void gemm_ep(const ushort* __restrict__ agg,
                                               const float* __restrict__ W,
                                               const float* __restrict__ bias,
                                               const float* __restrict__ dinv_in,
                                               const float* __restrict__ dinv_out,
                                               const float* __restrict__ x,
                                               ushort* __restrict__ hs,
                                               float* __restrict__ out) {
    __shared__ ushort Ws[128 * 136];
    {   // stage W (fp32 -> bf16) into LDS
        int j = threadIdx.x >> 1;
        int k0 = (threadIdx.x & 1) * 64;
        const float4* wp = (const float4*)(W + (size_t)j * DD + k0);
        ushort* dst = Ws + j * 136 + k0;
#pragma unroll
        for (int q = 0; q < 16; ++q) {
            float4 v = wp[q];
            ushort4 o;
            o.x = f2bf(v.x); o.y = f2bf(v.y); o.z = f2bf(v.z); o.w = f2bf(v.w);
            *(ushort4*)(dst + q * 4) = o;
        }
    }
    __syncthreads();

    const int wave = threadIdx.x >> 6;
    const int lane = threadIdx.x & 63;
    const int tile = blockIdx.x * 4 + wave;
    if (tile >= NTILE) return;
    const int mi = lane & 15;
    const int quad = lane >> 4;
    const int m0 = tile * 16;

    floatx4 acc[8];
#pragma unroll
    for (int t = 0; t < 8; ++t) acc[t] = (floatx4){0.f, 0.f, 0.f, 0.f};

    const ushort* ap = agg + (size_t)(m0 + mi) * DD + quad * 8;
#pragma unroll
    for (int s = 0; s < 4; ++s) {
        short8 a = *(const short8*)(ap + s * 32);
#pragma unroll
        for (int t = 0; t < 8; ++t) {
            short8 b = *(const short8*)(Ws + (t * 16 + mi) * 136 + s * 32 + quad * 8);
            acc[t] = __builtin_amdgcn_mfma_f32_16x16x32_bf16(a, b, acc[t], 0, 0, 0);
        }
    }

    // C/D layout: col = lane&15, row = quad*4 + reg
    float dv[4], dov[4];
#pragma unroll
    for (int i = 0; i < 4; ++i) {
        int r = m0 + quad * 4 + i;
        dv[i] = dinv_in[r];
        if (L1) dov[i] = dinv_out[r];
    }
#pragma unroll
    for (int t = 0; t < 8; ++t) {
        int c = t * 16 + mi;
        float bv = bias[c];
#pragma unroll
        for (int i = 0; i < 4; ++i) {
            int r = m0 + quad * 4 + i;
            float o = (acc[t][i] + bv) * dv[i];
            if (L1) {
                o += x[(size_t)r * DD + c];
                o = fmaxf(o, 0.f);
                hs[(size_t)r * DD + c] = f2bf(o * dov[i]);
            } else {
                out[(size_t)r * DD + c] = o;
            }
        }
    }
}

extern "C" void kernel_launch(void* const* d_in, const int* in_sizes, int n_in,
                              void* d_out, int out_size, void* d_ws, size_t ws_size,
                              hipStream_t stream) {
    const float* x  = (const float*)d_in[0];
    const int*   ei = (const int*)d_in[1];
    const float* W1 = (const float*)d_in[2];
    const float* b1 = (const float*)d_in[3];
    const float* W2 = (const float*)d_in[4];
    const float* b2 = (const float*)d_in[5];
    float* out = (float*)d_out;

    const int* row = ei;        // edge_index[0] (source)
    const int* col = ei + EE;   // edge_index[1] (target)

    // workspace layout (off[] aliases agg: off is dead before gather writes agg)
    ushort* agg     = (ushort*)d_ws;                 // N*DD bf16 (25.6 MB)
    ushort* xb      = agg + (size_t)NN * DD;         // N*DD bf16 (25.6 MB) -> becomes hs
    float* dinv_out = (float*)(xb + (size_t)NN * DD);
    float* dinv_in  = dinv_out + NN;
    int*   cnt      = (int*)(dinv_in + NN);          // 2*N (cnt_out, cnt_in)
    int*   excl     = cnt + 2 * NN;                  // N
    int*   row_st   = excl + NN;                     // N
    int*   srcs     = row_st + NN;                   // E
    int*   bsums    = srcs + EE;                     // 256
    int*   off      = (int*)agg;                     // E (aliased)

    // ---- degrees + CSR build (reused by both layers) ----
    hipMemsetAsync(cnt, 0, 2 * NN * sizeof(int), stream);
    count_kernel<<<(EE + 255) / 256, 256, 0, stream>>>(row, col, cnt, cnt + NN, off);
    dinv_kernel<<<(NN + 255) / 256, 256, 0, stream>>>(cnt, cnt + NN, dinv_out, dinv_in);
    scan1_kernel<<<NB1, 256, 0, stream>>>(cnt + NN, excl, bsums);
    scan2_kernel<<<1, 256, 0, stream>>>(bsums, NB1);
    scan3_kernel<<<(NN + 255) / 256, 256, 0, stream>>>(excl, bsums, row_st);
    fill_kernel<<<(EE + 255) / 256, 256, 0, stream>>>(row, col, row_st, off, srcs);

    // ---- layer 1 ----
    prescale_kernel<<<(NN * 32 + 255) / 256, 256, 0, stream>>>(x, dinv_out, xb);
    gather_kernel<<<(NN + 15) / 16, 256, 0, stream>>>(xb, row_st, srcs, agg);
    gemm_ep<true><<<(NTILE + 3) / 4, 256, 0, stream>>>(agg, W1, b1, dinv_in, dinv_out, x,
                                                       /*hs=*/xb, /*out=*/nullptr);

    // ---- layer 2 ----
    gather_kernel<<<(NN + 15) / 16, 256, 0, stream>>>(xb, row_st, srcs, agg);
    gemm_ep<false><<<(NTILE + 3) / 4, 256, 0, stream>>>(agg, W2, b2, dinv_in, nullptr, nullptr,
                                                        nullptr, out);
}